// Round 2
// baseline (1070.198 us; speedup 1.0000x reference)
//
#include <hip/hip_runtime.h>
#include <hip/hip_bf16.h>

typedef __attribute__((ext_vector_type(8))) short short8;
typedef __attribute__((ext_vector_type(4))) float f32x4;

#define D_DIM 256
#define G_DIM 256
#define NSEG 4096
#define BM 64
#define PBLK 256  // persistent blocks, 1 per CU

__device__ __forceinline__ unsigned f2bf_u(float f) {
  unsigned u = __builtin_bit_cast(unsigned, f);
  return (u + 0x7fffu + ((u >> 16) & 1u)) >> 16;   // RNE, inputs are finite
}
__device__ __forceinline__ unsigned pk_bf2(float a, float b) {
  __hip_bfloat162 h = __float22bfloat162_rn(float2{a, b});  // v_cvt_pk_bf16_f32
  unsigned r;
  __builtin_memcpy(&r, &h, 4);
  return r;
}

// ---- W/Wg -> bf16, transposed: Wc[j][k] = (j<256 ? W[k][j] : Wg[k][j-256]) ----
__global__ void wconv_kernel(const float* __restrict__ W, const float* __restrict__ Wg,
                             unsigned short* __restrict__ Wc) {
  int j = blockIdx.x;          // 0..511
  int k = threadIdx.x;         // 0..255
  float v = (j < 256) ? W[k * 256 + j] : Wg[k * 256 + (j - 256)];
  Wc[j * 256 + k] = (unsigned short)f2bf_u(v);
}

// ---- counts per segment via binary search (batch is sorted) ----
__global__ void count_kernel(const int* __restrict__ batch, int N, float* __restrict__ counts) {
  int g = blockIdx.x * blockDim.x + threadIdx.x;
  if (g >= NSEG) return;
  int lo = 0, hi = N;
  while (lo < hi) { int mid = (lo + hi) >> 1; if (batch[mid] < g) lo = mid + 1; else hi = mid; }
  int lo2 = lo, hi2 = N;
  while (lo2 < hi2) { int mid = (lo2 + hi2) >> 1; if (batch[mid] < g + 1) lo2 = mid + 1; else hi2 = mid; }
  counts[g] = (float)(lo2 - lo);
}

// ---- fused: dual GEMM (states|gates) -> softmax gate -> segment partial sums ----
// Persistent: 256 blocks x 1024 thr (16 waves), 1 block/CU, CONTIGUOUS chunk of
// ~61 tiles per block. Wave w owns 16-col pair (states col cb..cb+16, gates col
// 256+cb..). launch_bounds(1024,2): 256 unified regs/thread -> no spill for
// x-tile double buffer (ld0..3 live across compute) + B rolling prefetch.
// Segment sums accumulate in registers across tiles (chunk is contiguous ->
// same segment spans ~3.8 tiles); atomic flush only on segment change.
__global__ __launch_bounds__(1024, 2) void fused_main(
    const float* __restrict__ x, const int* __restrict__ batch,
    const unsigned short* __restrict__ Wc,
    const float* __restrict__ bvec, const float* __restrict__ bgvec,
    float* __restrict__ seg, int N) {
  __shared__ __align__(16) char xs[2][32768];     // x tile [64][256] bf16, swizzled, dbuf
  __shared__ __align__(16) float part[16][64];    // per-wave row partial sums
  __shared__ __align__(16) float sinv[64];        // 1/rowsum

  const int t = threadIdx.x;
  const int lane = t & 63;
  const int wid = t >> 6;        // 0..15
  const int lr = lane & 15;
  const int lk = lane >> 4;
  const int cb = wid * 16;
  const int ntiles = N / BM;     // 15625

  // contiguous chunk [t0, t1) for this block
  const int q = ntiles / PBLK, r = ntiles % PBLK;
  const int bid = blockIdx.x;
  const int t0 = bid * q + (bid < r ? bid : r);
  const int t1 = t0 + q + (bid < r ? 1 : 0);

  // staging addressing: 2 rows of 8 floats per thread (rows srl, srl+32)
  const int srl = t >> 5;              // 0..31
  const int skb = (t & 31) * 8;        // bf16-elem col base
  const int sby0 = (srl * 512 + skb * 2) ^ ((srl & 7) << 4);
  const int sby1 = ((srl + 32) * 512 + skb * 2) ^ (((srl + 32) & 7) << 4);

  // B pointers: per-wave constant columns, reused every tile (L2-resident)
  const unsigned short* Bs = Wc + (cb + lr) * 256 + lk * 8;          // states col
  const unsigned short* Bg = Wc + (256 + cb + lr) * 256 + lk * 8;    // gates col

  // A-read bases (row*512 bits >=9, disjoint from k-offset bits 4..8 and swizzle bits 4..6)
  int abase[4], asw[4];
#pragma unroll
  for (int m = 0; m < 4; ++m) {
    int ar = m * 16 + lr;
    abase[m] = ar * 512;
    asw[m] = (ar & 7) << 4;
  }
  const int ko2 = lk * 16;

  const float bgv = bgvec[cb + lr];
  const float bv = bvec[cb + lr];

  // register segment accumulator (per-lane partial in (m,q) layout)
  int gcur = batch[(long)t0 * BM];
  float pacc = 0.f;

  int tile = t0;
  float4 ld0, ld1, ld2, ld3;
  {  // prologue: issue first tile's loads
    const float* p0 = x + ((long)tile * BM + srl) * D_DIM + skb;
    ld0 = ((const float4*)p0)[0];
    ld1 = ((const float4*)p0)[1];
    const float* p1 = p0 + 32 * D_DIM;
    ld2 = ((const float4*)p1)[0];
    ld3 = ((const float4*)p1)[1];
  }

  for (int it = 0; tile < t1; ++it, ++tile) {
    char* xb = xs[it & 1];
    const long row0 = (long)tile * BM;

    // stage current tile (consume ld*), then immediately issue next tile's loads
    {
      uint4 pk0, pk1;
      pk0.x = pk_bf2(ld0.x, ld0.y); pk0.y = pk_bf2(ld0.z, ld0.w);
      pk0.z = pk_bf2(ld1.x, ld1.y); pk0.w = pk_bf2(ld1.z, ld1.w);
      pk1.x = pk_bf2(ld2.x, ld2.y); pk1.y = pk_bf2(ld2.z, ld2.w);
      pk1.z = pk_bf2(ld3.x, ld3.y); pk1.w = pk_bf2(ld3.z, ld3.w);
      *(uint4*)(xb + sby0) = pk0;
      *(uint4*)(xb + sby1) = pk1;
    }
    if (tile + 1 < t1) {
      const float* p0 = x + ((long)(tile + 1) * BM + srl) * D_DIM + skb;
      ld0 = ((const float4*)p0)[0];
      ld1 = ((const float4*)p0)[1];
      const float* p1 = p0 + 32 * D_DIM;
      ld2 = ((const float4*)p1)[0];
      ld3 = ((const float4*)p1)[1];
    }

    // B rolling prefetch (depth 2), issued under the barrier wait
    short8 bcur0 = *(const short8*)(Bs);
    short8 bcur1 = *(const short8*)(Bg);
    short8 bnxt0 = *(const short8*)(Bs + 32);
    short8 bnxt1 = *(const short8*)(Bg + 32);

    __syncthreads();

    f32x4 acc[4][2];
#pragma unroll
    for (int m = 0; m < 4; ++m) {
      acc[m][0] = (f32x4){0.f, 0.f, 0.f, 0.f};
      acc[m][1] = (f32x4){0.f, 0.f, 0.f, 0.f};
    }

#pragma unroll
    for (int kk = 0; kk < 8; ++kk) {
      short8 a[4];
#pragma unroll
      for (int m = 0; m < 4; ++m)
        a[m] = *(const short8*)(xb + abase[m] + ((kk * 64 + ko2) ^ asw[m]));
      short8 b0 = bcur0, b1 = bcur1;
      bcur0 = bnxt0; bcur1 = bnxt1;
      if (kk < 6) {
        bnxt0 = *(const short8*)(Bs + (kk + 2) * 32);
        bnxt1 = *(const short8*)(Bg + (kk + 2) * 32);
      }
#pragma unroll
      for (int m = 0; m < 4; ++m) {
        acc[m][0] = __builtin_amdgcn_mfma_f32_16x16x32_bf16(a[m], b0, acc[m][0], 0, 0, 0);
        acc[m][1] = __builtin_amdgcn_mfma_f32_16x16x32_bf16(a[m], b1, acc[m][1], 0, 0, 0);
      }
    }

    // gates: e = exp(logit + bg) in place (no max-sub: logits ~N(0,1), exp bounded)
#pragma unroll
    for (int m = 0; m < 4; ++m)
#pragma unroll
      for (int qq = 0; qq < 4; ++qq)
        acc[m][1][qq] = __expf(acc[m][1][qq] + bgv);

    // wave-local row sums over this wave's 16 gate cols (reduce over lr via shfl)
#pragma unroll
    for (int m = 0; m < 4; ++m) {
      float s[4];
#pragma unroll
      for (int qq = 0; qq < 4; ++qq) {
        float v = acc[m][1][qq];
        v += __shfl_xor(v, 1);
        v += __shfl_xor(v, 2);
        v += __shfl_xor(v, 4);
        v += __shfl_xor(v, 8);
        s[qq] = v;
      }
      if (lr == 0) {
#pragma unroll
        for (int qq = 0; qq < 4; ++qq) part[wid][m * 16 + lk * 4 + qq] = s[qq];
      }
    }
    __syncthreads();
    if (wid == 0) {
      float v = 0.f;
#pragma unroll
      for (int w = 0; w < 16; ++w) v += part[w][lane];
      sinv[lane] = 1.0f / v;
    }
    __syncthreads();

    // gating: gated = (states + b) * e * sinv
#pragma unroll
    for (int m = 0; m < 4; ++m) {
      f32x4 siv = *(const f32x4*)(&sinv[m * 16 + lk * 4]);
#pragma unroll
      for (int qq = 0; qq < 4; ++qq)
        acc[m][0][qq] = (acc[m][0][qq] + bv) * acc[m][1][qq] * siv[qq];
    }

    // segment reduce: batch sorted; accumulate per-lane partials in registers,
    // flush (shfl-reduce + atomic) only when the segment id advances.
    int rb[4][4];
#pragma unroll
    for (int m = 0; m < 4; ++m) {
      const int4 v = *(const int4*)(batch + row0 + m * 16 + lk * 4);
      rb[m][0] = v.x; rb[m][1] = v.y; rb[m][2] = v.z; rb[m][3] = v.w;
    }
    const int g0 = batch[row0];
    const int g1 = batch[row0 + BM - 1];
    for (int g = g0; g <= g1; ++g) {
      if (g != gcur) {
        float p = pacc;
        p += __shfl_xor(p, 16);
        p += __shfl_xor(p, 32);
        if (lane < 16) atomicAdd(seg + (long)gcur * G_DIM + cb + lane, p);
        pacc = 0.f;
        gcur = g;
      }
#pragma unroll
      for (int m = 0; m < 4; ++m)
#pragma unroll
        for (int qq = 0; qq < 4; ++qq)
          pacc += (rb[m][qq] == g) ? acc[m][0][qq] : 0.f;
    }
  }

  // final flush of the last open segment
  {
    float p = pacc;
    p += __shfl_xor(p, 16);
    p += __shfl_xor(p, 32);
    if (lane < 16) atomicAdd(seg + (long)gcur * G_DIM + cb + lane, p);
  }
}

// ---- out = (seg/max(cnt,1)) @ Wf + bf, in-place on d_out (block-local staging) ----
__global__ __launch_bounds__(256) void final_kernel(
    float* __restrict__ seg, const float* __restrict__ counts,
    const float* __restrict__ Wf, const float* __restrict__ bfv) {
  __shared__ float mlds[16][257];
  int g0 = blockIdx.x * 16;
  int t = threadIdx.x;
#pragma unroll
  for (int i = 0; i < 16; ++i) {
    float inv = 1.0f / fmaxf(counts[g0 + i], 1.0f);
    mlds[i][t] = seg[(g0 + i) * 256 + t] * inv;
  }
  __syncthreads();
  float a[16];
#pragma unroll
  for (int i = 0; i < 16; ++i) a[i] = 0.f;
  for (int k = 0; k < 256; ++k) {
    float w = Wf[k * 256 + t];
#pragma unroll
    for (int i = 0; i < 16; ++i) a[i] += mlds[i][k] * w;
  }
  float bfx = bfv[t];
#pragma unroll
  for (int i = 0; i < 16; ++i) seg[(g0 + i) * 256 + t] = a[i] + bfx;
}

extern "C" void kernel_launch(void* const* d_in, const int* in_sizes, int n_in,
                              void* d_out, int out_size, void* d_ws, size_t ws_size,
                              hipStream_t stream) {
  const float* x = (const float*)d_in[0];
  const int* batch = (const int*)d_in[1];
  const float* W = (const float*)d_in[2];
  const float* b = (const float*)d_in[3];
  const float* Wg = (const float*)d_in[4];
  const float* bg = (const float*)d_in[5];
  const float* Wf = (const float*)d_in[6];
  const float* bf = (const float*)d_in[7];
  const int N = in_sizes[0] / D_DIM;  // 1,000,000

  unsigned short* Wc = (unsigned short*)d_ws;              // 512*256*2 = 262144 B
  float* counts = (float*)((char*)d_ws + 262144);          // 4096*4 = 16384 B
  float* seg = (float*)d_out;                              // seg_sum scratch == output buffer

  (void)hipMemsetAsync(d_out, 0, (size_t)out_size * sizeof(float), stream);
  hipLaunchKernelGGL(wconv_kernel, dim3(512), dim3(256), 0, stream, W, Wg, Wc);
  hipLaunchKernelGGL(count_kernel, dim3(NSEG / 256), dim3(256), 0, stream, batch, N, counts);
  hipLaunchKernelGGL(fused_main, dim3(PBLK), dim3(1024), 0, stream, x, batch, Wc, b, bg, seg, N);
  hipLaunchKernelGGL(final_kernel, dim3(NSEG / 16), dim3(256), 0, stream, seg, counts, Wf, bf);
}

// Round 3
// 861.237 us; speedup vs baseline: 1.2426x; 1.2426x over previous
//
#include <hip/hip_runtime.h>
#include <hip/hip_bf16.h>

typedef __attribute__((ext_vector_type(8))) short short8;
typedef __attribute__((ext_vector_type(4))) float f32x4;

#define D_DIM 256
#define G_DIM 256
#define NSEG 4096
#define BM 64
#define PBLK 256  // persistent blocks, 1 per CU

__device__ __forceinline__ unsigned f2bf_u(float f) {
  unsigned u = __builtin_bit_cast(unsigned, f);
  return (u + 0x7fffu + ((u >> 16) & 1u)) >> 16;   // RNE, inputs are finite
}
__device__ __forceinline__ unsigned pk_bf2(float a, float b) {
  __hip_bfloat162 h = __float22bfloat162_rn(float2{a, b});  // v_cvt_pk_bf16_f32
  unsigned r;
  __builtin_memcpy(&r, &h, 4);
  return r;
}

// ---- W/Wg -> bf16, transposed: Wc[j][k] = (j<256 ? W[k][j] : Wg[k][j-256]) ----
__global__ void wconv_kernel(const float* __restrict__ W, const float* __restrict__ Wg,
                             unsigned short* __restrict__ Wc) {
  int j = blockIdx.x;          // 0..511
  int k = threadIdx.x;         // 0..255
  float v = (j < 256) ? W[k * 256 + j] : Wg[k * 256 + (j - 256)];
  Wc[j * 256 + k] = (unsigned short)f2bf_u(v);
}

// ---- counts per segment via binary search (batch is sorted) ----
__global__ void count_kernel(const int* __restrict__ batch, int N, float* __restrict__ counts) {
  int g = blockIdx.x * blockDim.x + threadIdx.x;
  if (g >= NSEG) return;
  int lo = 0, hi = N;
  while (lo < hi) { int mid = (lo + hi) >> 1; if (batch[mid] < g) lo = mid + 1; else hi = mid; }
  int lo2 = lo, hi2 = N;
  while (lo2 < hi2) { int mid = (lo2 + hi2) >> 1; if (batch[mid] < g + 1) lo2 = mid + 1; else hi2 = mid; }
  counts[g] = (float)(lo2 - lo);
}

// ---- fused: dual GEMM (states|gates) -> softmax gate -> segment partial sums ----
// Persistent: 256 blocks x 512 thr (8 waves), contiguous ~61-tile chunk per block.
// Wave w owns cols [w*32, w*32+32) of BOTH halves (acc[4][4] = 64 AGPR, as the
// 650us baseline). launch_bounds(512,2): 8 waves = 2/SIMD -> 256 unified regs.
// Cross-barrier pipeline state (x prefetch 32 + B rolling 32 VGPR) now FITS --
// R1/R2 spilled this to scratch (+~1GB HBM traffic) under 1024-thr's 128-reg cap.
// Double-buffered LDS x-tile: next tile's 64KB always in HBM flight per CU.
// Segment sums accumulate in registers; atomic flush only on segment change.
__global__ __launch_bounds__(512, 2) void fused_main(
    const float* __restrict__ x, const int* __restrict__ batch,
    const unsigned short* __restrict__ Wc,
    const float* __restrict__ bvec, const float* __restrict__ bgvec,
    float* __restrict__ seg, int N) {
  __shared__ __align__(16) char xs[2][32768];     // x tile [64][256] bf16, swizzled, dbuf
  __shared__ __align__(16) float part[8][64];     // per-wave row partial sums
  __shared__ __align__(16) float sinv[64];        // 1/rowsum

  const int t = threadIdx.x;
  const int lane = t & 63;
  const int wid = t >> 6;        // 0..7
  const int lr = lane & 15;
  const int lk = lane >> 4;
  const int cb = wid * 32;
  const int ntiles = N / BM;     // 15625

  // contiguous chunk [t0, t1) for this block
  const int q = ntiles / PBLK, r = ntiles % PBLK;
  const int bid = blockIdx.x;
  const int t0 = bid * q + (bid < r ? bid : r);
  const int t1 = t0 + q + (bid < r ? 1 : 0);

  // staging addressing: 4 iters x (row it*16 + t>>5, col (t&31)*8 floats)
  const int srl = t >> 5;              // 0..15
  const int skb = (t & 31) * 8;        // float/elem col base
  int sby[4];
#pragma unroll
  for (int it = 0; it < 4; ++it) {
    int rl = it * 16 + srl;
    sby[it] = (rl * 512 + skb * 2) ^ ((rl & 7) << 4);
  }

  // B pointers: per-wave constant columns, reused every tile (L2-resident)
  const unsigned short* Bp[4];
#pragma unroll
  for (int n = 0; n < 4; ++n) {
    int col = (n < 2) ? (cb + n * 16 + lr) : (256 + cb + (n - 2) * 16 + lr);
    Bp[n] = Wc + col * 256 + lk * 8;
  }

  // A-read bases
  int abase[4], asw[4];
#pragma unroll
  for (int m = 0; m < 4; ++m) {
    int ar = m * 16 + lr;
    abase[m] = ar * 512;
    asw[m] = (ar & 7) << 4;
  }
  const int ko2 = lk * 16;

  float bgv[2], bv[2];
#pragma unroll
  for (int n = 0; n < 2; ++n) {
    bgv[n] = bgvec[cb + n * 16 + lr];
    bv[n] = bvec[cb + n * 16 + lr];
  }

  // x prefetch registers: one full tile (32 VGPR), held across compute
  float4 L[4][2];
#define LOADX(tt)                                                     \
  {                                                                   \
    const float* p_ = x + ((long)(tt)*BM + srl) * D_DIM + skb;        \
    _Pragma("unroll") for (int i_ = 0; i_ < 4; ++i_) {                \
      L[i_][0] = ((const float4*)p_)[0];                              \
      L[i_][1] = ((const float4*)p_)[1];                              \
      p_ += 16 * D_DIM;                                               \
    }                                                                 \
  }
#define STAGEX(xb_)                                                   \
  {                                                                   \
    _Pragma("unroll") for (int i_ = 0; i_ < 4; ++i_) {                \
      uint4 pk_;                                                      \
      pk_.x = pk_bf2(L[i_][0].x, L[i_][0].y);                         \
      pk_.y = pk_bf2(L[i_][0].z, L[i_][0].w);                         \
      pk_.z = pk_bf2(L[i_][1].x, L[i_][1].y);                         \
      pk_.w = pk_bf2(L[i_][1].z, L[i_][1].w);                         \
      *(uint4*)((xb_) + sby[i_]) = pk_;                               \
    }                                                                 \
  }

  // prologue: stage tile t0, prefetch t0+1
  LOADX(t0);
  STAGEX(xs[0]);
  if (t0 + 1 < t1) LOADX(t0 + 1);
  __syncthreads();

  // register segment accumulator
  int gcur = batch[(long)t0 * BM];
  float pacc[2] = {0.f, 0.f};

  for (int tt = t0; tt < t1; ++tt) {
    const int it = tt - t0;
    char* xb = xs[it & 1];
    const long row0 = (long)tt * BM;

    // ---- compute: dual GEMM with B rolling prefetch (depth 2) ----
    short8 bcur[4], bnxt[4];
#pragma unroll
    for (int n = 0; n < 4; ++n) {
      bcur[n] = *(const short8*)(Bp[n]);
      bnxt[n] = *(const short8*)(Bp[n] + 32);
    }

    f32x4 acc[4][4];
#pragma unroll
    for (int m = 0; m < 4; ++m)
#pragma unroll
      for (int n = 0; n < 4; ++n) acc[m][n] = (f32x4){0.f, 0.f, 0.f, 0.f};

#pragma unroll
    for (int kk = 0; kk < 8; ++kk) {
      short8 a[4];
#pragma unroll
      for (int m = 0; m < 4; ++m)
        a[m] = *(const short8*)(xb + abase[m] + ((kk * 64 + ko2) ^ asw[m]));
      short8 b0[4];
#pragma unroll
      for (int n = 0; n < 4; ++n) {
        b0[n] = bcur[n];
        bcur[n] = bnxt[n];
      }
      if (kk < 6) {
#pragma unroll
        for (int n = 0; n < 4; ++n) bnxt[n] = *(const short8*)(Bp[n] + (kk + 2) * 32);
      }
#pragma unroll
      for (int m = 0; m < 4; ++m)
#pragma unroll
        for (int n = 0; n < 4; ++n)
          acc[m][n] = __builtin_amdgcn_mfma_f32_16x16x32_bf16(a[m], b0[n], acc[m][n], 0, 0, 0);
    }

    // ---- gates: e = exp(logit + bg) ----
#pragma unroll
    for (int m = 0; m < 4; ++m)
#pragma unroll
      for (int n = 2; n < 4; ++n)
#pragma unroll
        for (int qq = 0; qq < 4; ++qq)
          acc[m][n][qq] = __expf(acc[m][n][qq] + bgv[n - 2]);

    // ---- row sums: wave-local over 32 gate cols, then cross-wave via LDS ----
#pragma unroll
    for (int m = 0; m < 4; ++m) {
      float s[4];
#pragma unroll
      for (int qq = 0; qq < 4; ++qq) {
        float v = acc[m][2][qq] + acc[m][3][qq];
        v += __shfl_xor(v, 1);
        v += __shfl_xor(v, 2);
        v += __shfl_xor(v, 4);
        v += __shfl_xor(v, 8);
        s[qq] = v;
      }
      if (lr == 0) {
#pragma unroll
        for (int qq = 0; qq < 4; ++qq) part[wid][m * 16 + lk * 4 + qq] = s[qq];
      }
    }
    __syncthreads();
    if (wid == 0) {
      float v = part[0][lane] + part[1][lane] + part[2][lane] + part[3][lane] +
                part[4][lane] + part[5][lane] + part[6][lane] + part[7][lane];
      sinv[lane] = 1.0f / v;
    }
    __syncthreads();

    // ---- gating: gated = (states + b) * e * sinv ----
#pragma unroll
    for (int m = 0; m < 4; ++m) {
      f32x4 siv = *(const f32x4*)(&sinv[m * 16 + lk * 4]);
#pragma unroll
      for (int n = 0; n < 2; ++n)
#pragma unroll
        for (int qq = 0; qq < 4; ++qq)
          acc[m][n][qq] = (acc[m][n][qq] + bv[n]) * acc[m][n + 2][qq] * siv[qq];
    }

    // ---- segment accumulate in regs; atomic flush on segment change ----
    int rb[4][4];
#pragma unroll
    for (int m = 0; m < 4; ++m) {
      const int4 v = *(const int4*)(batch + row0 + m * 16 + lk * 4);
      rb[m][0] = v.x; rb[m][1] = v.y; rb[m][2] = v.z; rb[m][3] = v.w;
    }
    const int g0 = batch[row0];
    const int g1 = batch[row0 + BM - 1];
    for (int g = g0; g <= g1; ++g) {
      if (g != gcur) {
        float p0 = pacc[0], p1 = pacc[1];
        p0 += __shfl_xor(p0, 16); p0 += __shfl_xor(p0, 32);
        p1 += __shfl_xor(p1, 16); p1 += __shfl_xor(p1, 32);
        if (lane < 16) {
          atomicAdd(seg + (long)gcur * G_DIM + cb + lane, p0);
          atomicAdd(seg + (long)gcur * G_DIM + cb + 16 + lane, p1);
        }
        pacc[0] = 0.f; pacc[1] = 0.f;
        gcur = g;
      }
#pragma unroll
      for (int m = 0; m < 4; ++m)
#pragma unroll
        for (int qq = 0; qq < 4; ++qq) {
          bool hit = (rb[m][qq] == g);
          pacc[0] += hit ? acc[m][0][qq] : 0.f;
          pacc[1] += hit ? acc[m][1][qq] : 0.f;
        }
    }

    // ---- staging: write tile tt+1 (regs already in flight), prefetch tt+2 ----
    if (tt + 1 < t1) {
      STAGEX(xs[(it + 1) & 1]);
      if (tt + 2 < t1) LOADX(tt + 2);
    }
    __syncthreads();
  }

  // final flush of the last open segment
  {
    float p0 = pacc[0], p1 = pacc[1];
    p0 += __shfl_xor(p0, 16); p0 += __shfl_xor(p0, 32);
    p1 += __shfl_xor(p1, 16); p1 += __shfl_xor(p1, 32);
    if (lane < 16) {
      atomicAdd(seg + (long)gcur * G_DIM + cb + lane, p0);
      atomicAdd(seg + (long)gcur * G_DIM + cb + 16 + lane, p1);
    }
  }
#undef LOADX
#undef STAGEX
}

// ---- out = (seg/max(cnt,1)) @ Wf + bf, in-place on d_out (block-local staging) ----
__global__ __launch_bounds__(256) void final_kernel(
    float* __restrict__ seg, const float* __restrict__ counts,
    const float* __restrict__ Wf, const float* __restrict__ bfv) {
  __shared__ float mlds[16][257];
  int g0 = blockIdx.x * 16;
  int t = threadIdx.x;
#pragma unroll
  for (int i = 0; i < 16; ++i) {
    float inv = 1.0f / fmaxf(counts[g0 + i], 1.0f);
    mlds[i][t] = seg[(g0 + i) * 256 + t] * inv;
  }
  __syncthreads();
  float a[16];
#pragma unroll
  for (int i = 0; i < 16; ++i) a[i] = 0.f;
  for (int k = 0; k < 256; ++k) {
    float w = Wf[k * 256 + t];
#pragma unroll
    for (int i = 0; i < 16; ++i) a[i] += mlds[i][k] * w;
  }
  float bfx = bfv[t];
#pragma unroll
  for (int i = 0; i < 16; ++i) seg[(g0 + i) * 256 + t] = a[i] + bfx;
}

extern "C" void kernel_launch(void* const* d_in, const int* in_sizes, int n_in,
                              void* d_out, int out_size, void* d_ws, size_t ws_size,
                              hipStream_t stream) {
  const float* x = (const float*)d_in[0];
  const int* batch = (const int*)d_in[1];
  const float* W = (const float*)d_in[2];
  const float* b = (const float*)d_in[3];
  const float* Wg = (const float*)d_in[4];
  const float* bg = (const float*)d_in[5];
  const float* Wf = (const float*)d_in[6];
  const float* bf = (const float*)d_in[7];
  const int N = in_sizes[0] / D_DIM;  // 1,000,000

  unsigned short* Wc = (unsigned short*)d_ws;              // 512*256*2 = 262144 B
  float* counts = (float*)((char*)d_ws + 262144);          // 4096*4 = 16384 B
  float* seg = (float*)d_out;                              // seg_sum scratch == output buffer

  (void)hipMemsetAsync(d_out, 0, (size_t)out_size * sizeof(float), stream);
  hipLaunchKernelGGL(wconv_kernel, dim3(512), dim3(256), 0, stream, W, Wg, Wc);
  hipLaunchKernelGGL(count_kernel, dim3(NSEG / 256), dim3(256), 0, stream, batch, N, counts);
  hipLaunchKernelGGL(fused_main, dim3(PBLK), dim3(512), 0, stream, x, batch, Wc, b, bg, seg, N);
  hipLaunchKernelGGL(final_kernel, dim3(NSEG / 16), dim3(256), 0, stream, seg, counts, Wf, bf);
}

// Round 5
// 638.871 us; speedup vs baseline: 1.6751x; 1.3481x over previous
//
#include <hip/hip_runtime.h>
#include <hip/hip_bf16.h>

typedef __attribute__((ext_vector_type(8))) short short8;
typedef __attribute__((ext_vector_type(4))) float f32x4;

#define D_DIM 256
#define G_DIM 256
#define NSEG 4096
#define BM 64

__device__ __forceinline__ unsigned f2bf_u(float f) {
  unsigned u = __builtin_bit_cast(unsigned, f);
  return (u + 0x7fffu + ((u >> 16) & 1u)) >> 16;   // RNE, inputs are finite
}
__device__ __forceinline__ unsigned pk_bf2(float a, float b) {
  __hip_bfloat162 h = __float22bfloat162_rn(float2{a, b});  // v_cvt_pk_bf16_f32
  unsigned r;
  __builtin_memcpy(&r, &h, 4);
  return r;
}

// 16-lane-group sum via DPP (replaces ds_swizzle shfl chains: VALU-only, no LDS pipe)
template <int CTRL>
__device__ __forceinline__ float dpp_add(float v) {
  int x = __builtin_bit_cast(int, v);
  int y = __builtin_amdgcn_update_dpp(0, x, CTRL, 0xF, 0xF, true);
  return v + __builtin_bit_cast(float, y);
}
__device__ __forceinline__ float row16_sum(float v) {
  v = dpp_add<0xB1>(v);   // quad_perm [1,0,3,2]  (xor 1)
  v = dpp_add<0x4E>(v);   // quad_perm [2,3,0,1]  (xor 2)
  v = dpp_add<0x124>(v);  // row_ror:4
  v = dpp_add<0x128>(v);  // row_ror:8
  return v;               // all 16 lanes of the row hold the sum
}

// ---- W/Wg -> bf16, transposed: Wc[j][k] = (j<256 ? W[k][j] : Wg[k][j-256]) ----
__global__ void wconv_kernel(const float* __restrict__ W, const float* __restrict__ Wg,
                             unsigned short* __restrict__ Wc) {
  int j = blockIdx.x;          // 0..511
  int k = threadIdx.x;         // 0..255
  float v = (j < 256) ? W[k * 256 + j] : Wg[k * 256 + (j - 256)];
  Wc[j * 256 + k] = (unsigned short)f2bf_u(v);
}

// ---- counts per segment via binary search (batch is sorted) ----
__global__ void count_kernel(const int* __restrict__ batch, int N, float* __restrict__ counts) {
  int g = blockIdx.x * blockDim.x + threadIdx.x;
  if (g >= NSEG) return;
  int lo = 0, hi = N;
  while (lo < hi) { int mid = (lo + hi) >> 1; if (batch[mid] < g) lo = mid + 1; else hi = mid; }
  int lo2 = lo, hi2 = N;
  while (lo2 < hi2) { int mid = (lo2 + hi2) >> 1; if (batch[mid] < g + 1) lo2 = mid + 1; else hi2 = mid; }
  counts[g] = (float)(lo2 - lo);
}

// ---- fused: dual GEMM (states|gates) -> softmax gate -> segment partial sums ----
// block: 64 rows x 512 cols, 8 waves of 64; wave w owns cols [w*32, w*32+32) of BOTH halves.
// Small per-wave footprint (acc 16 + bb 16 + a 16 regs) -> 4 waves/SIMD without spill.
// (R0 structure restored; edits: DPP rowsum, setprio around MFMA, early batch loads.)
__global__ __launch_bounds__(512, 4) void fused_main(
    const float* __restrict__ x, const int* __restrict__ batch,
    const unsigned short* __restrict__ Wc,
    const float* __restrict__ bvec, const float* __restrict__ bgvec,
    float* __restrict__ seg, int N) {
  __shared__ __align__(16) char xs[32768];        // x tile [64][256] bf16, swizzled
  __shared__ __align__(16) float part[8][64];     // per-wave row partial sums
  __shared__ __align__(16) float sinv[64];        // 1/rowsum

  const int t = threadIdx.x;
  const int lane = t & 63;
  const int wid = t >> 6;                         // 0..7
  const int lr = lane & 15;
  const int lk = lane >> 4;
  const long row0 = (long)blockIdx.x * BM;        // N % 64 == 0 (1e6 = 15625*64)

  // stage x tile [64][256] as bf16, swizzle: byte ^= (row&7)<<4   (4 iters x 512 thr)
#pragma unroll
  for (int it = 0; it < 4; ++it) {
    int rl = it * 16 + (t >> 5);
    int kb = (t & 31) * 8;
    const float4* p = (const float4*)(x + (row0 + rl) * D_DIM + kb);
    float4 v0 = p[0], v1 = p[1];
    uint4 pk;
    pk.x = pk_bf2(v0.x, v0.y);
    pk.y = pk_bf2(v0.z, v0.w);
    pk.z = pk_bf2(v1.x, v1.y);
    pk.w = pk_bf2(v1.z, v1.w);
    int byte = (rl * 512 + kb * 2) ^ ((rl & 7) << 4);
    *(uint4*)(xs + byte) = pk;
  }
  __syncthreads();

  // K-loop, fully unrolled; B-frags direct from global (Wc 256KB, L2-resident).
  // acc n: 0,1 = states cols cb..cb+32; 2,3 = gates cols cb..cb+32.
  f32x4 acc[4][4];
#pragma unroll
  for (int m = 0; m < 4; ++m)
#pragma unroll
    for (int n = 0; n < 4; ++n) acc[m][n] = (f32x4){0.f, 0.f, 0.f, 0.f};

  const int cb = wid * 32;
  __builtin_amdgcn_s_setprio(1);
#pragma unroll
  for (int kk = 0; kk < 8; ++kk) {
    const int k0 = kk * 32 + lk * 8;
    short8 a[4], bb[4];
#pragma unroll
    for (int n = 0; n < 4; ++n) {
      int col = (n < 2) ? (cb + n * 16 + lr) : (256 + cb + (n - 2) * 16 + lr);
      bb[n] = *(const short8*)(Wc + col * 256 + k0);
    }
#pragma unroll
    for (int m = 0; m < 4; ++m) {
      int row = m * 16 + lr;
      int byte = (row * 512 + k0 * 2) ^ ((row & 7) << 4);
      a[m] = *(const short8*)(xs + byte);
    }
#pragma unroll
    for (int m = 0; m < 4; ++m)
#pragma unroll
      for (int n = 0; n < 4; ++n)
        acc[m][n] = __builtin_amdgcn_mfma_f32_16x16x32_bf16(a[m], bb[n], acc[m][n], 0, 0, 0);
  }
  __builtin_amdgcn_s_setprio(0);

  // early: batch ids for the segment epilogue (a[]/bb[] just died -> regs free;
  // L2 latency hides under exp/rowsum/gating below)
  int rb[4][4];
#pragma unroll
  for (int m = 0; m < 4; ++m) {
    const int4 v = *(const int4*)(batch + row0 + m * 16 + lk * 4);
    rb[m][0] = v.x; rb[m][1] = v.y; rb[m][2] = v.z; rb[m][3] = v.w;
  }
  const int g0 = batch[row0];
  const int g1 = batch[row0 + BM - 1];

  // gates: e = exp(logit + bg) in fp32 regs (no max-sub: logits ~N(0,1), exp <= ~500)
  float bgv[2];
#pragma unroll
  for (int n = 0; n < 2; ++n) bgv[n] = bgvec[cb + n * 16 + lr];
#pragma unroll
  for (int m = 0; m < 4; ++m)
#pragma unroll
    for (int n = 2; n < 4; ++n)
#pragma unroll
      for (int q = 0; q < 4; ++q)
        acc[m][n][q] = __expf(acc[m][n][q] + bgv[n - 2]);

  // wave-local row sums over this wave's 32 gate cols:
  // C layout: row = m*16 + lk*4 + q, col = n*16 + lr. Reduce over n (regs) then lr (DPP).
#pragma unroll
  for (int m = 0; m < 4; ++m) {
    float s[4];
#pragma unroll
    for (int q = 0; q < 4; ++q) s[q] = row16_sum(acc[m][2][q] + acc[m][3][q]);
    if (lr == 0) {
#pragma unroll
      for (int q = 0; q < 4; ++q) part[wid][m * 16 + lk * 4 + q] = s[q];
    }
  }
  __syncthreads();
  if (wid == 0) {
    float v = part[0][lane] + part[1][lane] + part[2][lane] + part[3][lane] +
              part[4][lane] + part[5][lane] + part[6][lane] + part[7][lane];
    sinv[lane] = 1.0f / v;
  }
  __syncthreads();

  // gating: gated = (states + b) * e * sinv
  float bv[2];
#pragma unroll
  for (int n = 0; n < 2; ++n) bv[n] = bvec[cb + n * 16 + lr];
  f32x4 siv[4];
#pragma unroll
  for (int m = 0; m < 4; ++m) siv[m] = *(const f32x4*)(&sinv[m * 16 + lk * 4]);
#pragma unroll
  for (int m = 0; m < 4; ++m)
#pragma unroll
    for (int n = 0; n < 2; ++n)
#pragma unroll
      for (int q = 0; q < 4; ++q)
        acc[m][n][q] = (acc[m][n][q] + bv[n]) * acc[m][n + 2][q] * siv[m][q];

  // segment reduce: batch sorted -> tile spans [g0, g1] (typically 1-2 segments)
  for (int g = g0; g <= g1; ++g) {
    float p[2] = {0.f, 0.f};
#pragma unroll
    for (int m = 0; m < 4; ++m)
#pragma unroll
      for (int q = 0; q < 4; ++q) {
        bool hit = (rb[m][q] == g);
#pragma unroll
        for (int n = 0; n < 2; ++n) p[n] += hit ? acc[m][n][q] : 0.f;
      }
#pragma unroll
    for (int n = 0; n < 2; ++n) {
      p[n] += __shfl_xor(p[n], 16);
      p[n] += __shfl_xor(p[n], 32);
    }
    if (lane < 16) {
#pragma unroll
      for (int n = 0; n < 2; ++n)
        atomicAdd(seg + (long)g * G_DIM + cb + n * 16 + lane, p[n]);
    }
  }
}

// ---- out = (seg/max(cnt,1)) @ Wf + bf, in-place on d_out (block-local staging) ----
__global__ __launch_bounds__(256) void final_kernel(
    float* __restrict__ seg, const float* __restrict__ counts,
    const float* __restrict__ Wf, const float* __restrict__ bfv) {
  __shared__ float mlds[16][257];
  int g0 = blockIdx.x * 16;
  int t = threadIdx.x;
#pragma unroll
  for (int i = 0; i < 16; ++i) {
    float inv = 1.0f / fmaxf(counts[g0 + i], 1.0f);
    mlds[i][t] = seg[(g0 + i) * 256 + t] * inv;
  }
  __syncthreads();
  float a[16];
#pragma unroll
  for (int i = 0; i < 16; ++i) a[i] = 0.f;
  for (int k = 0; k < 256; ++k) {
    float w = Wf[k * 256 + t];
#pragma unroll
    for (int i = 0; i < 16; ++i) a[i] += mlds[i][k] * w;
  }
  float bfx = bfv[t];
#pragma unroll
  for (int i = 0; i < 16; ++i) seg[(g0 + i) * 256 + t] = a[i] + bfx;
}

extern "C" void kernel_launch(void* const* d_in, const int* in_sizes, int n_in,
                              void* d_out, int out_size, void* d_ws, size_t ws_size,
                              hipStream_t stream) {
  const float* x = (const float*)d_in[0];
  const int* batch = (const int*)d_in[1];
  const float* W = (const float*)d_in[2];
  const float* b = (const float*)d_in[3];
  const float* Wg = (const float*)d_in[4];
  const float* bg = (const float*)d_in[5];
  const float* Wf = (const float*)d_in[6];
  const float* bf = (const float*)d_in[7];
  const int N = in_sizes[0] / D_DIM;  // 1,000,000

  unsigned short* Wc = (unsigned short*)d_ws;              // 512*256*2 = 262144 B
  float* counts = (float*)((char*)d_ws + 262144);          // 4096*4 = 16384 B
  float* seg = (float*)d_out;                              // seg_sum scratch == output buffer

  (void)hipMemsetAsync(d_out, 0, (size_t)out_size * sizeof(float), stream);
  hipLaunchKernelGGL(wconv_kernel, dim3(512), dim3(256), 0, stream, W, Wg, Wc);
  hipLaunchKernelGGL(count_kernel, dim3(NSEG / 256), dim3(256), 0, stream, batch, N, counts);
  hipLaunchKernelGGL(fused_main, dim3(N / BM), dim3(512), 0, stream, x, batch, Wc, b, bg, seg, N);
  hipLaunchKernelGGL(final_kernel, dim3(NSEG / 16), dim3(256), 0, stream, seg, counts, Wf, bf);
}